// Round 7
// baseline (2360.421 us; speedup 1.0000x reference)
//
#include <hip/hip_runtime.h>
#include <math.h>

#define BB 128
#define TT 512
#define HH 128
#define G4 512      // 4*H
#define CC 128
#define WW 32

// ---- workspace layout (float slots) ----
#define OFF_FCWT  0                          // 16384
#define OFF_W1P   (OFF_FCWT + CC*HH)         // f16 permuted Whh1: 32768 slots
#define OFF_WI2P  (OFF_W1P  + G4*HH/2)
#define OFF_WH2P  (OFF_WI2P + G4*HH/2)
#define OFF_B1P   (OFF_WH2P + G4*HH/2)       // 512
#define OFF_WI1P  (OFF_B1P + G4)
#define OFF_B2P   (OFF_WI1P + G4)
#define OFF_H2A   (OFF_B2P + G4)             // [T][B][H] fp32 (read-only after k1)
#define OFF_DOLD  (OFF_H2A + TT*BB*HH)
#define OFF_DH    (OFF_DOLD + TT*BB)
#define OFF_MT    (OFF_DH + TT*BB)
#define OFF_ST    (OFF_MT + TT)

typedef _Float16 h2t __attribute__((ext_vector_type(2)));

__device__ __forceinline__ unsigned short f16b(float v) {
    return __builtin_bit_cast(unsigned short, (_Float16)v);
}
__device__ __forceinline__ float dot2f(unsigned int a, unsigned int b, float acc) {
#if defined(__has_builtin) && __has_builtin(__builtin_amdgcn_fdot2)
    return __builtin_amdgcn_fdot2(__builtin_bit_cast(h2t, a),
                                  __builtin_bit_cast(h2t, b), acc, false);
#else
    h2t av = __builtin_bit_cast(h2t, a), bv = __builtin_bit_cast(h2t, b);
    acc = fmaf((float)av.x, (float)bv.x, acc);
    acc = fmaf((float)av.y, (float)bv.y, acc);
    return acc;
#endif
}
__device__ __forceinline__ float rcpf(float x) {
#if defined(__has_builtin) && __has_builtin(__builtin_amdgcn_rcpf)
    return __builtin_amdgcn_rcpf(x);
#else
    return 1.f / x;
#endif
}
// sigma(v) if !isg, tanh(v) = 2*sigma(2v)-1 if isg
__device__ __forceinline__ float act(float v, bool isg) {
    float xin = isg ? v + v : v;
    float r = rcpf(1.f + __expf(-xin));
    return isg ? fmaf(2.f, r, -1.f) : r;
}

// DPP quad_perm helpers (pure VALU, quad-local, no DS-pipe traffic).
// xor1 = quad_perm[1,0,3,2] = 0xB1 ; xor2 = quad_perm[2,3,0,1] = 0x4E.
template <int CTRL>
__device__ __forceinline__ float dppadd(float v) {
#if defined(__has_builtin) && __has_builtin(__builtin_amdgcn_update_dpp)
    int m = __builtin_amdgcn_update_dpp(0, __builtin_bit_cast(int, v),
                                        CTRL, 0xf, 0xf, true);
    return v + __builtin_bit_cast(float, m);
#else
    return v + __shfl_xor(v, CTRL == 0xB1 ? 1 : 2);
#endif
}
template <int CTRL>
__device__ __forceinline__ float dppmov(float v) {
#if defined(__has_builtin) && __has_builtin(__builtin_amdgcn_update_dpp)
    int m = __builtin_amdgcn_update_dpp(0, __builtin_bit_cast(int, v),
                                        CTRL, 0xf, 0xf, true);
    return __builtin_bit_cast(float, m);
#else
    return __shfl_xor(v, CTRL == 0xB1 ? 1 : 2);
#endif
}

// 32 dot2 from scalar-VGPR weights (no register tuples -> no quad-alignment
// fragmentation for the allocator).
__device__ __forceinline__ void dot32v(float& acc, const unsigned (&W)[32],
                                       const uint4 (&S)[8]) {
    #pragma unroll
    for (int k = 0; k < 8; ++k) {
        acc = dot2f(W[4*k+0], S[k].x, acc);
        acc = dot2f(W[4*k+1], S[k].y, acc);
        acc = dot2f(W[4*k+2], S[k].z, acc);
        acc = dot2f(W[4*k+3], S[k].w, acc);
    }
}
// 32 dot2 from AGPR-resident weights: v_accvgpr_read + dot2 per dword.
// The "a" constraint FORCES AGPR allocation - mechanical residency, immune
// to the VGPR allocator's spill heuristic (which defeated rounds 1-6).
__device__ __forceinline__ void dot32a(float& acc, const unsigned (&A)[32],
                                       const uint4 (&S)[8]) {
    #pragma unroll
    for (int k = 0; k < 8; ++k) {
        unsigned t0, t1, t2, t3;
        asm volatile("v_accvgpr_read_b32 %0, %1" : "=v"(t0) : "a"(A[4*k+0]));
        asm volatile("v_accvgpr_read_b32 %0, %1" : "=v"(t1) : "a"(A[4*k+1]));
        asm volatile("v_accvgpr_read_b32 %0, %1" : "=v"(t2) : "a"(A[4*k+2]));
        asm volatile("v_accvgpr_read_b32 %0, %1" : "=v"(t3) : "a"(A[4*k+3]));
        acc = dot2f(t0, S[k].x, acc);
        acc = dot2f(t1, S[k].y, acc);
        acc = dot2f(t2, S[k].z, acc);
        acc = dot2f(t3, S[k].w, acc);
    }
}

// LDS-visibility barrier WITHOUT vmcnt drain (per-step h2a store stays in
// flight; nothing reads h2a until k1 completes).
#define STEP_BARRIER() asm volatile("s_waitcnt lgkmcnt(0)\n\ts_barrier" ::: "memory")

// K0: gate-interleaved (r = h*4 + g) f16 weight images + permuted biases +
// fcW transpose.  (unchanged)
__global__ __launch_bounds__(256) void k0_prep(
    const float* __restrict__ Whh1, const float* __restrict__ Wih2,
    const float* __restrict__ Whh2, const float* __restrict__ fcW,
    const float* __restrict__ Wih1,
    const float* __restrict__ bih1, const float* __restrict__ bhh1,
    const float* __restrict__ bih2, const float* __restrict__ bhh2,
    float* __restrict__ fcWT,
    unsigned short* __restrict__ w1p, unsigned short* __restrict__ wi2p,
    unsigned short* __restrict__ wh2p,
    float* __restrict__ b1p, float* __restrict__ wi1p, float* __restrict__ b2p)
{
    int idx = blockIdx.x * blockDim.x + threadIdx.x;
    if (idx < G4 * HH) {
        int r_old = idx >> 7, k = idx & 127;
        int g = r_old >> 7, h = r_old & 127;
        int dst = (h * 4 + g) * HH + k;
        w1p [dst] = f16b(Whh1[idx]);
        wi2p[dst] = f16b(Wih2[idx]);
        wh2p[dst] = f16b(Whh2[idx]);
    }
    if (idx < CC * HH) {
        int c = idx / HH, h = idx % HH;
        fcWT[h * CC + c] = fcW[idx];
    }
    if (idx < G4) {
        int g = idx >> 7, h = idx & 127;
        int rn = h * 4 + g;
        b1p [rn] = bih1[idx] + bhh1[idx];
        wi1p[rn] = Wih1[idx];
        b2p [rn] = bih2[idx] + bhh2[idx];
    }
}

// K1: mechanically register-resident weights.  512 threads; thread =
// (unit h = tid>>2, row-pair half = (tid>>1)&1, col half s = tid&1).
// Per thread: w1 (64 dw) in SCALAR VGPRs, wi2+wh2 (128 dw) in AGPRs via
// v_accvgpr_write (hard "a" constraints - allocator cannot spill these).
// __launch_bounds__(512,2): total reg cap 256 = 128 AGPR + <=128 VGPR,
// preserving 2 waves/SIMD.  Steady-state step: zero weight memory traffic;
// ~375 VALU instrs (64+128 dot2, 128 accvgpr_read, cell math) + 24
// broadcast ds_read_b128.
__global__ __launch_bounds__(512, 2) void k1_lstm(
    const float* __restrict__ x,
    const float* __restrict__ b1p, const float* __restrict__ wi1p,
    const float* __restrict__ b2p,
    const unsigned short* __restrict__ w1p,
    const unsigned short* __restrict__ wi2p,
    const unsigned short* __restrict__ wh2p,
    float* __restrict__ h2a)
{
    __shared__ __align__(16) unsigned short h1h[2][HH];
    __shared__ __align__(16) unsigned short c1h[2][HH];
    __shared__ __align__(16) unsigned short h2h[2][HH];
    __shared__ float xs[TT];

    const int tid  = threadIdx.x;
    const int b    = blockIdx.x;
    const int s    = tid & 1;            // col half: cols [64s, 64s+64)
    const int half = (tid >> 1) & 1;     // 0: rows (i,f) ; 1: rows (g,o)
    const int h    = tid >> 2;           // hidden unit 0..127
    const int gr0  = 4 * h + 2 * half;   // first owned gate-row
    const bool hB  = (half != 0);

    // ---- w1: 2 rows x 64 cols -> 64 scalar VGPR dwords ----
    unsigned w1r[2][32];
    #pragma unroll
    for (int rr = 0; rr < 2; ++rr) {
        const uint4* p1 = (const uint4*)(w1p + (size_t)(gr0 + rr) * HH + 64 * s);
        #pragma unroll
        for (int k = 0; k < 8; ++k) {
            uint4 v = p1[k];
            w1r[rr][4*k+0] = v.x; w1r[rr][4*k+1] = v.y;
            w1r[rr][4*k+2] = v.z; w1r[rr][4*k+3] = v.w;
        }
    }
    #pragma unroll
    for (int rr = 0; rr < 2; ++rr)
        #pragma unroll
        for (int k = 0; k < 32; ++k)
            asm volatile("" : "+v"(w1r[rr][k]));

    // ---- wi2, wh2: 2 rows x 64 cols each -> 128 AGPR dwords ----
    unsigned ai2[2][32], ah2[2][32];
    #pragma unroll
    for (int rr = 0; rr < 2; ++rr) {
        const uint4* p2 = (const uint4*)(wi2p + (size_t)(gr0 + rr) * HH + 64 * s);
        const uint4* p3 = (const uint4*)(wh2p + (size_t)(gr0 + rr) * HH + 64 * s);
        #pragma unroll
        for (int k = 0; k < 8; ++k) {
            uint4 v = p2[k];
            asm volatile("v_accvgpr_write_b32 %0, %1" : "=a"(ai2[rr][4*k+0]) : "v"(v.x));
            asm volatile("v_accvgpr_write_b32 %0, %1" : "=a"(ai2[rr][4*k+1]) : "v"(v.y));
            asm volatile("v_accvgpr_write_b32 %0, %1" : "=a"(ai2[rr][4*k+2]) : "v"(v.z));
            asm volatile("v_accvgpr_write_b32 %0, %1" : "=a"(ai2[rr][4*k+3]) : "v"(v.w));
            uint4 w = p3[k];
            asm volatile("v_accvgpr_write_b32 %0, %1" : "=a"(ah2[rr][4*k+0]) : "v"(w.x));
            asm volatile("v_accvgpr_write_b32 %0, %1" : "=a"(ah2[rr][4*k+1]) : "v"(w.y));
            asm volatile("v_accvgpr_write_b32 %0, %1" : "=a"(ah2[rr][4*k+2]) : "v"(w.z));
            asm volatile("v_accvgpr_write_b32 %0, %1" : "=a"(ah2[rr][4*k+3]) : "v"(w.w));
        }
    }
    const float wi1v0 = wi1p[gr0],     b1v0 = b1p[gr0],     b2v0 = b2p[gr0];
    const float wi1v1 = wi1p[gr0 + 1], b1v1 = b1p[gr0 + 1], b2v1 = b2p[gr0 + 1];

    xs[tid] = x[(size_t)b * TT + tid];
    if (tid < HH) {
        h1h[0][tid] = 0; h1h[1][tid] = 0;
        c1h[0][tid] = 0; c1h[1][tid] = 0;
        h2h[0][tid] = 0; h2h[1][tid] = 0;
    }
    float c1reg = 0.f, c2reg = 0.f;   // cell state lives on half==0 lanes
    __syncthreads();

    float* outp = h2a + (size_t)b * HH + h;

    // ---- prologue u=0: layer-1 only, h1(prev)=0 -> gates are scalar ----
    {
        float g0 = fmaf(xs[0], wi1v0, b1v0);
        float g1 = fmaf(xs[0], wi1v1, b1v1);
        float e0 = act(g0, hB);                 // A: sig(i) ; B: tanh(g)
        float e1 = act(g1, false);              // A: sig(f) ; B: sig(o)
        float peer = dppmov<0x4E>(e0);          // A <- tanh(g)
        float cn1 = fmaf(e1, c1reg, e0 * peer); // valid on A
        c1reg = hB ? c1reg : cn1;
        float cnp = dppmov<0x4E>(cn1);          // B <- cn
        float hn1 = e1 * act(cnp, true);        // valid on B
        if (s == 0) {
            if (hB) h1h[1][h] = f16b(hn1);
            else    c1h[1][h] = f16b(cn1);
        }
    }
    STEP_BARRIER();

    // ---- main: u = 1 .. TT-1 (layer-1 at t=u, layer-2 at t=u-1) ----
    for (int u = 1; u < TT; ++u) {
        const int p = u & 1, q = p ^ 1;
        const float xv = xs[u];

        uint4 sv[8];
        // layer-1 dots: h1h[p] = h1(u-1)
        const uint4* hp = (const uint4*)&h1h[p][64 * s];
        #pragma unroll
        for (int k = 0; k < 8; ++k) sv[k] = hp[k];
        float a0 = 0.f, a1 = 0.f;
        dot32v(a0, w1r[0], sv);
        dot32v(a1, w1r[1], sv);
        // layer-2 dots: c1h[p] = c1(u-1), h2h[p] = h2(u-2)
        const uint4* cp = (const uint4*)&c1h[p][64 * s];
        #pragma unroll
        for (int k = 0; k < 8; ++k) sv[k] = cp[k];
        float d0 = 0.f, d1 = 0.f;
        dot32a(d0, ai2[0], sv);
        dot32a(d1, ai2[1], sv);
        const uint4* gp = (const uint4*)&h2h[p][64 * s];
        #pragma unroll
        for (int k = 0; k < 8; ++k) sv[k] = gp[k];
        dot32a(d0, ah2[0], sv);
        dot32a(d1, ah2[1], sv);

        // col-half reduce (pure DPP)
        a0 = dppadd<0xB1>(a0); a1 = dppadd<0xB1>(a1);
        d0 = dppadd<0xB1>(d0); d1 = dppadd<0xB1>(d1);

        // ---- cell-1 (t=u) ----
        float g0 = a0 + fmaf(xv, wi1v0, b1v0);
        float g1 = a1 + fmaf(xv, wi1v1, b1v1);
        float e0 = act(g0, hB);
        float e1 = act(g1, false);
        float peer = dppmov<0x4E>(e0);
        float cn1 = fmaf(e1, c1reg, e0 * peer);
        c1reg = hB ? c1reg : cn1;
        float cnp1 = dppmov<0x4E>(cn1);
        float hn1 = e1 * act(cnp1, true);

        // ---- cell-2 (t=u-1) ----
        float f0 = d0 + b2v0;
        float f1 = d1 + b2v1;
        float u0 = act(f0, hB);
        float u1 = act(f1, false);
        float peer2 = dppmov<0x4E>(u0);
        float cn2 = fmaf(u1, c2reg, u0 * peer2);
        c2reg = hB ? c2reg : cn2;
        float cnp2 = dppmov<0x4E>(cn2);
        float hn2 = u1 * act(cnp2, true);

        if (s == 0) {
            if (hB) {
                h1h[q][h] = f16b(hn1);
                h2h[q][h] = f16b(hn2);
                outp[(size_t)(u - 1) * (BB * HH)] = hn2;
            } else {
                c1h[q][h] = f16b(cn1);
            }
        }
        STEP_BARRIER();
    }

    // ---- epilogue u=TT: layer-2 only (t = TT-1), buffers p = TT&1 = 0 ----
    {
        uint4 sv[8];
        const uint4* cp = (const uint4*)&c1h[0][64 * s];
        #pragma unroll
        for (int k = 0; k < 8; ++k) sv[k] = cp[k];
        float d0 = 0.f, d1 = 0.f;
        dot32a(d0, ai2[0], sv);
        dot32a(d1, ai2[1], sv);
        const uint4* gp = (const uint4*)&h2h[0][64 * s];
        #pragma unroll
        for (int k = 0; k < 8; ++k) sv[k] = gp[k];
        dot32a(d0, ah2[0], sv);
        dot32a(d1, ah2[1], sv);
        d0 = dppadd<0xB1>(d0); d1 = dppadd<0xB1>(d1);
        float f0 = d0 + b2v0;
        float f1 = d1 + b2v1;
        float u0 = act(f0, hB);
        float u1 = act(f1, false);
        float peer2 = dppmov<0x4E>(u0);
        float cn2 = fmaf(u1, c2reg, u0 * peer2);
        float cnp2 = dppmov<0x4E>(cn2);
        float hn2 = u1 * act(cnp2, true);
        if (hB && s == 0) outp[(size_t)(TT - 1) * (BB * HH)] = hn2;
    }
}

// K2: d_old[t,b] = h2[t,b,:].wt_old ; d_h[t,b] = h2[t,b,:].wt_h  (unchanged)
__global__ __launch_bounds__(256) void k2_dots(
    const float* __restrict__ h2a, const float* __restrict__ w_t,
    float* __restrict__ dold, float* __restrict__ dh)
{
    const int lane = threadIdx.x & 63;
    const int wave = blockIdx.x * (blockDim.x >> 6) + (threadIdx.x >> 6);
    const int nw = gridDim.x * (blockDim.x >> 6);
    const float wh0 = w_t[lane],       wh1 = w_t[64 + lane];
    const float wo0 = w_t[128 + lane], wo1 = w_t[192 + lane];
    for (int row = wave; row < TT * BB; row += nw) {
        const float* p = h2a + (size_t)row * HH;
        float v0 = p[lane], v1 = p[64 + lane];
        float po = v0 * wo0 + v1 * wo1;
        float ph = v0 * wh0 + v1 * wh1;
        #pragma unroll
        for (int off = 32; off; off >>= 1) {
            po += __shfl_xor(po, off);
            ph += __shfl_xor(ph, off);
        }
        if (lane == 0) { dold[row] = po; dh[row] = ph; }
    }
}

// K3: per-t global softmax stats over valid (j,b): m[t], s[t]  (unchanged)
__global__ __launch_bounds__(256) void k3_stats(
    const float* __restrict__ dold, const float* __restrict__ dh,
    float* __restrict__ mt, float* __restrict__ st)
{
    const int t = blockIdx.x;
    const int tid = threadIdx.x;
    const int cnt = (min(t, WW) + 1) * BB;
    const int jstart = max(t - (WW + 1), -1);

    float m = -INFINITY;
    for (int idx = tid; idx < cnt; idx += 256) {
        int jj = idx >> 7, b = idx & 127;
        int j = jstart + jj;
        float sc = dh[t * BB + b] + (j >= 0 ? dold[j * BB + b] : 0.f);
        m = fmaxf(m, sc);
    }
    #pragma unroll
    for (int off = 32; off; off >>= 1) m = fmaxf(m, __shfl_xor(m, off));
    __shared__ float rbuf[4];
    int wv = tid >> 6, ln = tid & 63;
    if (ln == 0) rbuf[wv] = m;
    __syncthreads();
    m = fmaxf(fmaxf(rbuf[0], rbuf[1]), fmaxf(rbuf[2], rbuf[3]));

    float s = 0.f;
    for (int idx = tid; idx < cnt; idx += 256) {
        int jj = idx >> 7, b = idx & 127;
        int j = jstart + jj;
        float sc = dh[t * BB + b] + (j >= 0 ? dold[j * BB + b] : 0.f);
        s += __expf(sc - m);
    }
    #pragma unroll
    for (int off = 32; off; off >>= 1) s += __shfl_xor(s, off);
    __shared__ float sbuf[4];
    if (ln == 0) sbuf[wv] = s;
    __syncthreads();
    if (tid == 0) { mt[t] = m; st[t] = sbuf[0] + sbuf[1] + sbuf[2] + sbuf[3]; }
}

// K45: fused attention + FC. grid (TT/8, BB), block 256.  (unchanged)
__global__ __launch_bounds__(256) void k45_attn_fc(
    const float* __restrict__ h2a,
    const float* __restrict__ dold, const float* __restrict__ dh,
    const float* __restrict__ mt, const float* __restrict__ st,
    const float* __restrict__ fcWT, const float* __restrict__ fcb,
    float* __restrict__ out)
{
    const int t0 = blockIdx.x * 8;
    const int b  = blockIdx.y;
    const int tid = threadIdx.x;

    __shared__ float hbuf[41][HH];     // rows t0-33 .. t0+7
    __shared__ float wjs[8][36];
    __shared__ float ytile[8][HH];

    for (int i = tid; i < 41 * 32; i += 256) {
        int r = i >> 5, q4 = i & 31;
        int t = t0 - 33 + r;
        float4 v = make_float4(0.f, 0.f, 0.f, 0.f);
        if (t >= 0)
            v = *(const float4*)(h2a + (size_t)t * (BB * HH) + (size_t)b * HH + q4 * 4);
        *(float4*)&hbuf[r][q4 * 4] = v;
    }
    for (int i = tid; i < 8 * 33; i += 256) {
        int tt = i / 33, ss = i % 33;
        int t = t0 + tt, j = t - 33 + ss;
        float w = 0.f;
        if (j >= 0)
            w = __expf(dold[j * BB + b] + dh[t * BB + b] - mt[t]) / st[t];
        wjs[tt][ss] = w;
    }
    __syncthreads();

    {
        const int tq = tid >> 5;
        const int hq = (tid & 31) * 4;
        float4 acc = *(const float4*)&hbuf[tq + 33][hq];   // h2[t]
        #pragma unroll 11
        for (int ss = 0; ss < 33; ++ss) {
            float w = wjs[tq][ss];
            float4 hb = *(const float4*)&hbuf[tq + ss][hq];
            acc.x = fmaf(w, hb.x, acc.x);
            acc.y = fmaf(w, hb.y, acc.y);
            acc.z = fmaf(w, hb.z, acc.z);
            acc.w = fmaf(w, hb.w, acc.w);
        }
        *(float4*)&ytile[tq][hq] = acc;
    }
    __syncthreads();

    {
        const int c  = tid & 127;
        const int th = tid >> 7;
        float acc[4];
        const float bias = fcb[c];
        #pragma unroll
        for (int i = 0; i < 4; ++i) acc[i] = bias;
        for (int hh = 0; hh < HH; ++hh) {
            float w = fcWT[hh * CC + c];
            #pragma unroll
            for (int i = 0; i < 4; ++i)
                acc[i] = fmaf(ytile[th * 4 + i][hh], w, acc[i]);
        }
        #pragma unroll
        for (int i = 0; i < 4; ++i) {
            int t = t0 + th * 4 + i;
            out[(size_t)b * (TT * CC) + (size_t)t * CC + c] = acc[i];
        }
    }
}

extern "C" void kernel_launch(void* const* d_in, const int* in_sizes, int n_in,
                              void* d_out, int out_size, void* d_ws, size_t ws_size,
                              hipStream_t stream)
{
    const float* x    = (const float*)d_in[0];
    const float* Wih1 = (const float*)d_in[1];
    const float* Whh1 = (const float*)d_in[2];
    const float* bih1 = (const float*)d_in[3];
    const float* bhh1 = (const float*)d_in[4];
    const float* Wih2 = (const float*)d_in[5];
    const float* Whh2 = (const float*)d_in[6];
    const float* bih2 = (const float*)d_in[7];
    const float* bhh2 = (const float*)d_in[8];
    const float* w_t  = (const float*)d_in[9];
    const float* fcW  = (const float*)d_in[10];
    const float* fcb  = (const float*)d_in[11];
    float* out = (float*)d_out;

    float* ws   = (float*)d_ws;
    float* fcWT = ws + OFF_FCWT;
    unsigned short* w1p  = (unsigned short*)(ws + OFF_W1P);
    unsigned short* wi2p = (unsigned short*)(ws + OFF_WI2P);
    unsigned short* wh2p = (unsigned short*)(ws + OFF_WH2P);
    float* b1pp = ws + OFF_B1P;
    float* wi1p = ws + OFF_WI1P;
    float* b2pp = ws + OFF_B2P;
    float* h2a  = ws + OFF_H2A;
    float* dold = ws + OFF_DOLD;
    float* dh   = ws + OFF_DH;
    float* mt   = ws + OFF_MT;
    float* st   = ws + OFF_ST;

    k0_prep<<<dim3((G4 * HH + 255) / 256), dim3(256), 0, stream>>>(
        Whh1, Wih2, Whh2, fcW, Wih1, bih1, bhh1, bih2, bhh2,
        fcWT, w1p, wi2p, wh2p, b1pp, wi1p, b2pp);

    k1_lstm<<<dim3(BB), dim3(512), 0, stream>>>(
        x, b1pp, wi1p, b2pp, w1p, wi2p, wh2p, h2a);

    k2_dots<<<dim3(256), dim3(256), 0, stream>>>(h2a, w_t, dold, dh);

    k3_stats<<<dim3(TT), dim3(256), 0, stream>>>(dold, dh, mt, st);

    k45_attn_fc<<<dim3(TT / 8, BB), dim3(256), 0, stream>>>(
        h2a, dold, dh, mt, st, fcWT, fcb, out);
}